// Round 6
// baseline (127.660 us; speedup 1.0000x reference)
//
#include <hip/hip_runtime.h>
#include <math.h>

// AFM rank-1-unit scheme: one block = one sample, 448 threads (7 waves).
// Pair triangle tiled into 28 units of (16 rows r) x (16 cols c). Per unit:
// load ec B-frag ONCE (ds_read_b128), then per row r fold er into the A-operand
// (A' = W^T * er, 4 v_pk_mul_f16) and run mfma_f32_16x16x32_f16 with C=bias.
// Pool via pool[j] = ec[j] * sum_r(w_r * er_r[j])  (fma_mix, no cvt, no 2nd read).
// Softmax needs no max: |logit| < ~0.5 by construction -> exp safe.
constexpr int kT = 100;
constexpr int kD = 32;
constexpr int kA = 16;
constexpr int kESH = 40;    // e row stride in halfs (80 B, 16B-aligned)
constexpr int kNT = 448;    // 7 waves
constexpr int kNW = 7;

typedef float    float4v __attribute__((ext_vector_type(4)));
typedef __fp16   fp16x2  __attribute__((ext_vector_type(2)));
typedef __fp16   half4   __attribute__((ext_vector_type(4)));
typedef __fp16   half8   __attribute__((ext_vector_type(8)));
typedef _Float16 half8v  __attribute__((ext_vector_type(8)));

// Unit = R | C<<8 | nr<<16, wave-major: 4 units per wave, 7 waves.
// Tiles/wave: 62,62,62,64,64,64,51 (429 total; covers all r<c<100 exactly once).
__device__ __constant__ unsigned int kUnits[28] = {
    0u|(0u<<8)|(15u<<16),  16u|(16u<<8)|(15u<<16), 0u|(16u<<8)|(16u<<16),  0u|(32u<<8)|(16u<<16),
    32u|(32u<<8)|(15u<<16),48u|(48u<<8)|(15u<<16), 0u|(48u<<8)|(16u<<16),  0u|(64u<<8)|(16u<<16),
    64u|(64u<<8)|(15u<<16),80u|(80u<<8)|(15u<<16), 0u|(80u<<8)|(16u<<16),  0u|(96u<<8)|(16u<<16),
    16u|(32u<<8)|(16u<<16),16u|(48u<<8)|(16u<<16),16u|(64u<<8)|(16u<<16), 16u|(80u<<8)|(16u<<16),
    16u|(96u<<8)|(16u<<16),32u|(48u<<8)|(16u<<16),32u|(64u<<8)|(16u<<16), 32u|(80u<<8)|(16u<<16),
    32u|(96u<<8)|(16u<<16),48u|(64u<<8)|(16u<<16),48u|(80u<<8)|(16u<<16), 48u|(96u<<8)|(16u<<16),
    64u|(80u<<8)|(16u<<16),64u|(96u<<8)|(16u<<16),80u|(96u<<8)|(16u<<16), 96u|(96u<<8)|(3u<<16)
};

// LDS: she = 100*40 halfs = 8000 B; stg (448*9 floats = 16128 B) aliases after main loop.
__global__ __launch_bounds__(kNT, 7)
void afm_kernel(const int* __restrict__ x,
                const float* __restrict__ Emb,
                const float* __restrict__ W,    // (32,16)
                const float* __restrict__ bb,   // (16,)
                const float* __restrict__ h,    // (16,)
                const float* __restrict__ W1,   // (32,16)
                const float* __restrict__ b1,   // (16,)
                const float* __restrict__ W2,   // (16,8)
                const float* __restrict__ b2,   // (8,)
                const float* __restrict__ Wf,   // (8,)
                const float* __restrict__ bf,   // (1,)
                float* __restrict__ out)        // (1024,)
{
    __shared__ __align__(16) unsigned char smem[16128];
    __shared__ float red[kNW];
    __shared__ float sh_pooled[kD];
    __shared__ float sh_o1[kA];
    __shared__ float sh_o2[8];

    __fp16* she = (__fp16*)smem;

    const int tid  = threadIdx.x;
    const int b    = blockIdx.x;
    const int lane = tid & 63;
    const int wv   = tid >> 6;           // 0..6
    const int quad = lane >> 4;
    const int l15  = lane & 15;
    const int k0   = quad * 8;           // this quad's K slice (dims k0..k0+7)

    // ---- gather embeddings -> f16 LDS ----
    const int* xb = x + b * kT;
    for (int i = tid; i < kT * 8; i += kNT) {
        const int row = i >> 3, c4 = i & 7;
        const int v = xb[row];
        const float4 val = ((const float4*)Emb)[v * 8 + c4];
        union { fp16x2 h2[2]; half4 h4; } tmp;
        tmp.h2[0] = __builtin_amdgcn_cvt_pkrtz(val.x, val.y);
        tmp.h2[1] = __builtin_amdgcn_cvt_pkrtz(val.z, val.w);
        *(half4*)(she + row * kESH + c4 * 4) = tmp.h4;
    }

    // ---- A-frag: W^T in f16 (lane holds W[k0+j][a=l15]) + h, bias-C slices ----
    union { fp16x2 h2[4]; half8 fp; } wa;
#pragma unroll
    for (int j = 0; j < 4; ++j)
        wa.h2[j] = __builtin_amdgcn_cvt_pkrtz(W[(k0 + 2 * j) * kA + l15],
                                              W[(k0 + 2 * j + 1) * kA + l15]);
    float h_reg[4];
    float4v bfrag;
#pragma unroll
    for (int rg = 0; rg < 4; ++rg) {
        h_reg[rg] = h[quad * 4 + rg];
        bfrag[rg] = bb[quad * 4 + rg];
    }
    __syncthreads();

    // ---- main loop: 4 units per wave ----
    float pool[8];
#pragma unroll
    for (int j = 0; j < 8; ++j) pool[j] = 0.0f;
    float wsum = 0.0f;

    for (int u = 0; u < 4; ++u) {
        const unsigned ud = kUnits[wv * 4 + u];
        const int R  = ud & 255;
        const int C  = (ud >> 8) & 255;
        const int nr = ud >> 16;
        const int c  = C + l15;
        const int cl = c < 100 ? c : 99;

        union { half8 fp; half8v mf; } ec;
        ec.fp = *(const half8*)(she + cl * kESH + k0);   // once per unit

        float accu[8];
#pragma unroll
        for (int j = 0; j < 8; ++j) accu[j] = 0.0f;

        for (int rr = 0; rr < nr; rr += 2) {
            const int r1 = R + rr, r2 = R + rr + 1;      // r2 <= 99 always
            const half8 er1 = *(const half8*)(she + r1 * kESH + k0);  // broadcast
            const half8 er2 = *(const half8*)(she + r2 * kESH + k0);
            union { half8 fp; half8v mf; } a1, a2;
            a1.fp = wa.fp * er1;                          // 4x v_pk_mul_f16
            a2.fp = wa.fp * er2;

            float4v s1 = __builtin_amdgcn_mfma_f32_16x16x32_f16(a1.mf, ec.mf, bfrag, 0, 0, 0);
            float4v s2 = __builtin_amdgcn_mfma_f32_16x16x32_f16(a2.mf, ec.mf, bfrag, 0, 0, 0);

            float p1 = 0.0f, p2 = 0.0f;
#pragma unroll
            for (int rg = 0; rg < 4; ++rg) {
                p1 = fmaf(fmaxf(s1[rg], 0.0f), h_reg[rg], p1);
                p2 = fmaf(fmaxf(s2[rg], 0.0f), h_reg[rg], p2);
            }
            // packed quad butterfly: both rows' partials in one f16x2
            union { fp16x2 hh; int ii; } t0, t1;
            t0.hh = __builtin_amdgcn_cvt_pkrtz(p1, p2);
            t1.ii = __shfl_xor(t0.ii, 16, 64);
            t0.hh = t0.hh + t1.hh;
            t1.ii = __shfl_xor(t0.ii, 32, 64);
            t0.hh = t0.hh + t1.hh;
            const float l1 = (float)t0.hh[0];
            const float l2 = (float)t0.hh[1];

            const bool v1 = (c > r1) && (c < 100);
            const bool v2 = (rr + 1 < nr) && (c > r2) && (c < 100);
            const float w1 = v1 ? __expf(l1) : 0.0f;
            const float w2 = v2 ? __expf(l2) : 0.0f;
            wsum += w1 + w2;
#pragma unroll
            for (int j = 0; j < 8; ++j) {
                accu[j] = fmaf(w1, (float)er1[j], accu[j]);   // v_fma_mix
                accu[j] = fmaf(w2, (float)er2[j], accu[j]);
            }
        }
#pragma unroll
        for (int j = 0; j < 8; ++j)
            pool[j] = fmaf((float)ec.fp[j], accu[j], pool[j]);
    }

    // ---- reduce wsum (each pair counted by all 4 quads -> x4) ----
#pragma unroll
    for (int off = 1; off < 64; off <<= 1) wsum += __shfl_xor(wsum, off, 64);
    if (lane == 0) red[wv] = wsum;

    __syncthreads();                 // she reads done; smem reusable
    float* stg = (float*)smem;       // 448 * 9 floats
#pragma unroll
    for (int j = 0; j < 8; ++j) stg[tid * 9 + j] = pool[j];
    __syncthreads();

    if (tid < kD) {
        float ls = 0.0f;
        for (int w7 = 0; w7 < kNW; ++w7) ls += red[w7];
        const float invS = 4.0f / ls;
        const int q = tid >> 3, j = tid & 7;
        float s = 0.0f;
        for (int w7 = 0; w7 < kNW; ++w7)
            for (int l = 0; l < 16; ++l)
                s += stg[(w7 * 64 + q * 16 + l) * 9 + j];
        sh_pooled[tid] = s * invS;
    }
    __syncthreads();

    // ---- MLP head ----
    if (tid < kA) {
        float o = b1[tid];
#pragma unroll
        for (int d = 0; d < kD; ++d) o = fmaf(sh_pooled[d], W1[d * kA + tid], o);
        sh_o1[tid] = fmaxf(o, 0.0f);
    }
    __syncthreads();
    if (tid < 8) {
        float o = b2[tid];
#pragma unroll
        for (int a = 0; a < kA; ++a) o = fmaf(sh_o1[a], W2[a * 8 + tid], o);
        sh_o2[tid] = fmaxf(o, 0.0f);
    }
    __syncthreads();
    if (tid == 0) {
        float z = bf[0];
#pragma unroll
        for (int j = 0; j < 8; ++j) z = fmaf(sh_o2[j], Wf[j], z);
        out[b] = 1.0f / (1.0f + __expf(-z));
    }
}

extern "C" void kernel_launch(void* const* d_in, const int* in_sizes, int n_in,
                              void* d_out, int out_size, void* d_ws, size_t ws_size,
                              hipStream_t stream) {
    const int*   x   = (const int*)d_in[0];
    const float* Emb = (const float*)d_in[1];
    const float* W   = (const float*)d_in[2];
    const float* bb  = (const float*)d_in[3];
    const float* h   = (const float*)d_in[4];
    const float* W1  = (const float*)d_in[5];
    const float* b1  = (const float*)d_in[6];
    const float* W2  = (const float*)d_in[7];
    const float* b2  = (const float*)d_in[8];
    const float* Wf  = (const float*)d_in[9];
    const float* bf  = (const float*)d_in[10];
    float* out = (float*)d_out;

    afm_kernel<<<1024, kNT, 0, stream>>>(x, Emb, W, bb, h, W1, b1, W2, b2, Wf, bf, out);
}

// Round 7
// 115.576 us; speedup vs baseline: 1.1046x; 1.1046x over previous
//
#include <hip/hip_runtime.h>
#include <math.h>

// AFM fused single-pass (R5 structure + micro-opts): one block = one sample,
// 512 threads (8 waves). Per 16-pair tile: one mfma_f32_16x16x32_f16
// (S^T = W^T @ HB^T, C preloaded with bias), quad butterfly -> full logit,
// w = exp2(logit*log2e) (no-max softmax: |logit| < ~0.5), pool += w*hb in-reg.
// Pair table = pre-scaled LDS byte offsets (r*80)<<16 | (c*80), 4960 entries.
constexpr int kT = 100;
constexpr int kP = 4950;
constexpr int kD = 32;
constexpr int kA = 16;
constexpr int kESH = 40;                 // e row stride in halfs (80 B, 16B-aligned)
constexpr int kTiles = (kP + 15) / 16;   // 310
constexpr int kTblPad = 4960;            // = kTiles*16
constexpr int kNT = 512;                 // 8 waves

typedef float    float4v __attribute__((ext_vector_type(4)));
typedef __fp16   fp16x2  __attribute__((ext_vector_type(2)));
typedef __fp16   half4   __attribute__((ext_vector_type(4)));
typedef __fp16   half8   __attribute__((ext_vector_type(8)));
typedef _Float16 half8v  __attribute__((ext_vector_type(8)));

__device__ __forceinline__ void pair_decode(int p, int& r, int& c) {
    const float tq = 39601.0f - 8.0f * (float)p;
    r = (int)((199.0f - sqrtf(tq)) * 0.5f);
    if (r < 0) r = 0;
    if (r > 98) r = 98;
    int base = r * 99 - ((r * (r - 1)) >> 1);
    while (base > p) { --r; base = r * 99 - ((r * (r - 1)) >> 1); }
    while (p - base >= (99 - r)) { base += (99 - r); ++r; }
    c = r + 1 + (p - base);
}

__global__ void pair_init(unsigned int* __restrict__ tbl) {
    const int p = blockIdx.x * 256 + threadIdx.x;
    if (p < kTblPad) {
        int r, c;
        pair_decode(p < kP ? p : kP - 1, r, c);
        tbl[p] = ((unsigned)(r * kESH * 2) << 16) | (unsigned)(c * kESH * 2);
    }
}

// LDS: she 100*40 halfs = 8000 B | sh_tbl 4960 u32 = 19840 B (27840 total);
// stg (512*9 floats = 18432 B) aliases the same region after the main loop.
template <bool USE_TBL>
__global__ __launch_bounds__(kNT, 8)
void afm_kernel(const int* __restrict__ x,
                const float* __restrict__ Emb,
                const float* __restrict__ W,    // (32,16)
                const float* __restrict__ bb,   // (16,)
                const float* __restrict__ h,    // (16,)
                const float* __restrict__ W1,   // (32,16)
                const float* __restrict__ b1,   // (16,)
                const float* __restrict__ W2,   // (16,8)
                const float* __restrict__ b2,   // (8,)
                const float* __restrict__ Wf,   // (8,)
                const float* __restrict__ bf,   // (1,)
                const unsigned int* __restrict__ tbl,
                float* __restrict__ out)        // (1024,)
{
    __shared__ __align__(16) unsigned char smem[27840];
    __shared__ float red[8];
    __shared__ float sh_pooled[kD];
    __shared__ float sh_o1[kA];
    __shared__ float sh_o2[8];

    __fp16* she = (__fp16*)smem;
    unsigned int* sh_tbl = (unsigned int*)(smem + 8000);

    const int tid  = threadIdx.x;
    const int b    = blockIdx.x;
    const int lane = tid & 63;
    const int wv   = tid >> 6;           // 0..7
    const int quad = lane >> 4;
    const int l15  = lane & 15;
    const int k0   = quad * 8;           // this quad's K slice (dims k0..k0+7)

    // ---- gather embeddings -> f16 LDS ----
    const int* xb = x + b * kT;
    for (int i = tid; i < kT * 8; i += kNT) {
        const int row = i >> 3, c4 = i & 7;
        const int v = xb[row];
        const float4 val = ((const float4*)Emb)[v * 8 + c4];
        union { fp16x2 h2[2]; half4 h4; } tmp;
        tmp.h2[0] = __builtin_amdgcn_cvt_pkrtz(val.x, val.y);
        tmp.h2[1] = __builtin_amdgcn_cvt_pkrtz(val.z, val.w);
        *(half4*)(she + row * kESH + c4 * 4) = tmp.h4;
    }
    // ---- pair table: coalesced load from d_ws, or in-block decode fallback ----
    if (USE_TBL) {
        const uint4* t4 = (const uint4*)tbl;
        for (int i = tid; i < kTblPad / 4; i += kNT)   // 1240 uint4
            ((uint4*)sh_tbl)[i] = t4[i];
    } else {
        for (int p = tid; p < kTblPad; p += kNT) {
            int r, c;
            pair_decode(p < kP ? p : kP - 1, r, c);
            sh_tbl[p] = ((unsigned)(r * kESH * 2) << 16) | (unsigned)(c * kESH * 2);
        }
    }

    // ---- A-frag: W^T in f16 (lane holds W[k0+j][a=l15]) + h*log2e, bias-C ----
    union { fp16x2 h2[4]; half8v h8; } wa;
#pragma unroll
    for (int j = 0; j < 4; ++j)
        wa.h2[j] = __builtin_amdgcn_cvt_pkrtz(W[(k0 + 2 * j) * kA + l15],
                                              W[(k0 + 2 * j + 1) * kA + l15]);
    float h_reg[4];
    float4v bfrag;
#pragma unroll
    for (int rg = 0; rg < 4; ++rg) {
        h_reg[rg] = h[quad * 4 + rg] * 1.44269504088896340736f;  // fold log2(e)
        bfrag[rg] = bb[quad * 4 + rg];
    }
    const char* sheq = (const char*)she + k0 * 2;   // quad-sliced base (bytes)
    __syncthreads();

    // ---- fused main loop: ~39 tiles per wave ----
    float pool[8];
#pragma unroll
    for (int j = 0; j < 8; ++j) pool[j] = 0.0f;
    float lsum = 0.0f;

#pragma unroll 4
    for (int t = wv; t < kTiles; t += 8) {
        const int p_raw = t * 16 + l15;
        const unsigned pr = sh_tbl[p_raw];          // (r*80)<<16 | (c*80)

        const half8 er = *(const half8*)(sheq + (pr >> 16));
        const half8 ec = *(const half8*)(sheq + (pr & 0xFFFFu));
        union { half8 fp; half8v mf; } hb;
        hb.fp = er * ec;                            // 4x v_pk_mul_f16

        // C = bias: acc directly holds s = hb@W + b
        float4v acc = __builtin_amdgcn_mfma_f32_16x16x32_f16(wa.h8, hb.mf, bfrag, 0, 0, 0);

        // lane holds s[a=quad*4+rg][p=l15]
        float part = 0.0f;
#pragma unroll
        for (int rg = 0; rg < 4; ++rg)
            part = fmaf(fmaxf(acc[rg], 0.0f), h_reg[rg], part);
        part += __shfl_xor(part, 16, 64);           // full logit*log2e in every quad
        part += __shfl_xor(part, 32, 64);

        const float w = (p_raw < kP) ? exp2f(part) : 0.0f;
        lsum += w;
#pragma unroll
        for (int j = 0; j < 8; ++j)
            pool[j] = fmaf(w, (float)hb.fp[j], pool[j]);   // v_fma_mix
    }

    // ---- reduce l (quads duplicate w -> x4) ----
#pragma unroll
    for (int off = 1; off < 64; off <<= 1) lsum += __shfl_xor(lsum, off, 64);
    if (lane == 0) red[wv] = lsum;

    __syncthreads();                 // main-loop LDS reads done; smem reusable
    float* stg = (float*)smem;       // 512 * 9 floats = 18432 B
#pragma unroll
    for (int j = 0; j < 8; ++j) stg[tid * 9 + j] = pool[j];
    __syncthreads();

    // pooled[d]: contributors are lanes whose quad == d>>3, all 8 waves
    if (tid < kD) {
        const float invS = 4.0f / (red[0] + red[1] + red[2] + red[3] +
                                   red[4] + red[5] + red[6] + red[7]);
        const int q = tid >> 3, j = tid & 7;
        float s = 0.0f;
        for (int w8 = 0; w8 < 8; ++w8)
            for (int l = 0; l < 16; ++l)
                s += stg[(w8 * 64 + q * 16 + l) * 9 + j];
        sh_pooled[tid] = s * invS;
    }
    __syncthreads();

    // ---- MLP head ----
    if (tid < kA) {
        float o = b1[tid];
#pragma unroll
        for (int d = 0; d < kD; ++d) o = fmaf(sh_pooled[d], W1[d * kA + tid], o);
        sh_o1[tid] = fmaxf(o, 0.0f);
    }
    __syncthreads();
    if (tid < 8) {
        float o = b2[tid];
#pragma unroll
        for (int a = 0; a < kA; ++a) o = fmaf(sh_o1[a], W2[a * 8 + tid], o);
        sh_o2[tid] = fmaxf(o, 0.0f);
    }
    __syncthreads();
    if (tid == 0) {
        float z = bf[0];
#pragma unroll
        for (int j = 0; j < 8; ++j) z = fmaf(sh_o2[j], Wf[j], z);
        out[b] = 1.0f / (1.0f + __expf(-z));
    }
}

extern "C" void kernel_launch(void* const* d_in, const int* in_sizes, int n_in,
                              void* d_out, int out_size, void* d_ws, size_t ws_size,
                              hipStream_t stream) {
    const int*   x   = (const int*)d_in[0];
    const float* Emb = (const float*)d_in[1];
    const float* W   = (const float*)d_in[2];
    const float* bb  = (const float*)d_in[3];
    const float* h   = (const float*)d_in[4];
    const float* W1  = (const float*)d_in[5];
    const float* b1  = (const float*)d_in[6];
    const float* W2  = (const float*)d_in[7];
    const float* b2  = (const float*)d_in[8];
    const float* Wf  = (const float*)d_in[9];
    const float* bf  = (const float*)d_in[10];
    float* out = (float*)d_out;

    if (ws_size >= (size_t)(kTblPad * 4)) {
        unsigned int* tbl = (unsigned int*)d_ws;
        pair_init<<<(kTblPad + 255) / 256, 256, 0, stream>>>(tbl);
        afm_kernel<true><<<1024, kNT, 0, stream>>>(x, Emb, W, bb, h, W1, b1, W2, b2,
                                                   Wf, bf, tbl, out);
    } else {
        afm_kernel<false><<<1024, kNT, 0, stream>>>(x, Emb, W, bb, h, W1, b1, W2, b2,
                                                    Wf, bf, nullptr, out);
    }
}

// Round 8
// 107.038 us; speedup vs baseline: 1.1927x; 1.0798x over previous
//
#include <hip/hip_runtime.h>
#include <math.h>

// AFM fused single-pass, row-run schedule: one block = one sample, 512 threads
// (8 waves). Wave owns row r for a run of tiles (16 cols each):
//   er loaded once/row (wave-uniform), ec addr = +1280 B per tile, no pair table.
// Per tile: one mfma_f32_16x16x32_f16 (S^T = W^T@HB^T, C=bias), quad butterfly
// -> logit*log2e, w = v_exp_f32, pool accumulated packed f16 (v_pk_fma_f16).
// Softmax needs no max: |logit| < ~0.5 by construction.
constexpr int kT = 100;
constexpr int kD = 32;
constexpr int kA = 16;
constexpr int kESH = 40;     // e row stride in halfs (80 B)
constexpr int kRows = 116;   // 100 real + 16 zero pad (tail tiles read up to row 114)
constexpr int kNT = 512;     // 8 waves

typedef float    float4v __attribute__((ext_vector_type(4)));
typedef __fp16   fp16x2  __attribute__((ext_vector_type(2)));
typedef __fp16   half4   __attribute__((ext_vector_type(4)));
typedef __fp16   half8   __attribute__((ext_vector_type(8)));
typedef _Float16 half8v  __attribute__((ext_vector_type(8)));

#if __has_builtin(__builtin_amdgcn_exp2f)
#define EXP2F(x) __builtin_amdgcn_exp2f(x)
#else
#define EXP2F(x) exp2f(x)
#endif

// LDS: she = 116 rows * 80 B = 9280 B; stg (512*9 floats = 18432 B) aliases after main loop.
__global__ __launch_bounds__(kNT, 8)
void afm_kernel(const int* __restrict__ x,
                const float* __restrict__ Emb,
                const float* __restrict__ W,    // (32,16)
                const float* __restrict__ bb,   // (16,)
                const float* __restrict__ h,    // (16,)
                const float* __restrict__ W1,   // (32,16)
                const float* __restrict__ b1,   // (16,)
                const float* __restrict__ W2,   // (16,8)
                const float* __restrict__ b2,   // (8,)
                const float* __restrict__ Wf,   // (8,)
                const float* __restrict__ bf,   // (1,)
                float* __restrict__ out)        // (1024,)
{
    __shared__ __align__(16) unsigned char smem[18432];
    __shared__ float red[8];
    __shared__ float sh_pooled[kD];
    __shared__ float sh_o1[kA];
    __shared__ float sh_o2[8];

    __fp16* she = (__fp16*)smem;
    const char* sheb = (const char*)smem;

    const int tid  = threadIdx.x;
    const int b    = blockIdx.x;
    const int lane = tid & 63;
    const int wv   = tid >> 6;           // 0..7
    const int quad = lane >> 4;
    const int l15  = lane & 15;
    const int k0   = quad * 8;           // this quad's K slice (dims k0..k0+7)

    // ---- gather embeddings -> f16 LDS; zero the pad rows ----
    const int* xb = x + b * kT;
    for (int i = tid; i < kT * 8; i += kNT) {
        const int row = i >> 3, c4 = i & 7;
        const int v = xb[row];
        const float4 val = ((const float4*)Emb)[v * 8 + c4];
        union { fp16x2 h2[2]; half4 h4; } tmp;
        tmp.h2[0] = __builtin_amdgcn_cvt_pkrtz(val.x, val.y);
        tmp.h2[1] = __builtin_amdgcn_cvt_pkrtz(val.z, val.w);
        *(half4*)(she + row * kESH + c4 * 4) = tmp.h4;
    }
    if (tid < (kRows - kT) * kESH / 2)   // 320 u32 of zero pad (rows 100..115)
        ((unsigned int*)she)[kT * kESH / 2 + tid] = 0u;

    // ---- A-frag: W^T f16 (lane holds W[k0+j][a=l15]); h*log2e; bias as C ----
    union { fp16x2 h2[4]; half8v h8; } wa;
#pragma unroll
    for (int j = 0; j < 4; ++j)
        wa.h2[j] = __builtin_amdgcn_cvt_pkrtz(W[(k0 + 2 * j) * kA + l15],
                                              W[(k0 + 2 * j + 1) * kA + l15]);
    float h_reg[4];
    float4v bfrag;
#pragma unroll
    for (int rg = 0; rg < 4; ++rg) {
        h_reg[rg] = h[quad * 4 + rg] * 1.44269504088896340736f;  // fold log2(e)
        bfrag[rg] = bb[quad * 4 + rg];
    }
    const int lane_base = l15 * 80 + quad * 16;   // byte offset for ec
    __syncthreads();

    // ---- fused main loop over rows ----
    fp16x2 pool2[4];
    const fp16x2 zz = {(__fp16)0.0f, (__fp16)0.0f};
#pragma unroll
    for (int j = 0; j < 4; ++j) pool2[j] = zz;
    float lsum = 0.0f;

    union HB { half8 fp; fp16x2 h2[4]; half8v mf; };

    auto do_tile = [&](const half8& er, int coff, int rem, bool mask) {
        HB hb;
        hb.fp = er * (*(const half8*)(sheb + coff));   // 4x v_pk_mul_f16
        float4v acc = __builtin_amdgcn_mfma_f32_16x16x32_f16(wa.h8, hb.mf, bfrag, 0, 0, 0);
        float part = 0.0f;
#pragma unroll
        for (int rg = 0; rg < 4; ++rg)
            part = fmaf(fmaxf(acc[rg], 0.0f), h_reg[rg], part);
        part += __shfl_xor(part, 16, 64);
        part += __shfl_xor(part, 32, 64);
        float w = EXP2F(part);
        if (mask) w = (l15 < rem) ? w : 0.0f;
        lsum += w;
        const fp16x2 ww = __builtin_amdgcn_cvt_pkrtz(w, w);
#pragma unroll
        for (int j = 0; j < 4; ++j)
            pool2[j] += ww * hb.h2[j];                 // v_pk_fma_f16
    };

    auto do_row = [&](int r) {
        const int len = 99 - r;                        // pairs in this row (>=1)
        const int nfull = (len - 1) >> 4;              // full 16-col tiles
        const half8 er = *(const half8*)(sheb + r * 80 + quad * 16);
        int coff = (r + 1) * 80 + lane_base;
        for (int j = 0; j < nfull; ++j, coff += 1280)
            do_tile(er, coff, 16, false);
        do_tile(er, coff, len - (nfull << 4), true);   // tail tile (rem in 1..16)
    };

    // rows paired (g*16+wvg, g*16+15-wvg); rotate wvg per g to balance ceils
    for (int g = 0; g < 6; ++g) {
        const int wvg = (wv + g) & 7;
        do_row(g * 16 + wvg);
        do_row(g * 16 + 15 - wvg);
    }
    if (wv < 3) do_row(96 + wv);                       // rows 96..98

    // ---- reduce lsum (each pair counted by all 4 quads -> x4) ----
#pragma unroll
    for (int off = 1; off < 64; off <<= 1) lsum += __shfl_xor(lsum, off, 64);
    if (lane == 0) red[wv] = lsum;

    __syncthreads();                 // she reads done; smem reusable
    float* stg = (float*)smem;       // 512 * 9 floats = 18432 B
#pragma unroll
    for (int j = 0; j < 4; ++j) {
        stg[tid * 9 + 2 * j]     = (float)pool2[j][0];
        stg[tid * 9 + 2 * j + 1] = (float)pool2[j][1];
    }
    __syncthreads();

    // pooled[d]: contributors are lanes whose quad == d>>3, all 8 waves
    if (tid < kD) {
        const float invS = 4.0f / (red[0] + red[1] + red[2] + red[3] +
                                   red[4] + red[5] + red[6] + red[7]);
        const int q = tid >> 3, j = tid & 7;
        float s = 0.0f;
        for (int w8 = 0; w8 < 8; ++w8)
            for (int l = 0; l < 16; ++l)
                s += stg[(w8 * 64 + q * 16 + l) * 9 + j];
        sh_pooled[tid] = s * invS;
    }
    __syncthreads();

    // ---- MLP head ----
    if (tid < kA) {
        float o = b1[tid];
#pragma unroll
        for (int d = 0; d < kD; ++d) o = fmaf(sh_pooled[d], W1[d * kA + tid], o);
        sh_o1[tid] = fmaxf(o, 0.0f);
    }
    __syncthreads();
    if (tid < 8) {
        float o = b2[tid];
#pragma unroll
        for (int a = 0; a < kA; ++a) o = fmaf(sh_o1[a], W2[a * 8 + tid], o);
        sh_o2[tid] = fmaxf(o, 0.0f);
    }
    __syncthreads();
    if (tid == 0) {
        float z = bf[0];
#pragma unroll
        for (int j = 0; j < 8; ++j) z = fmaf(sh_o2[j], Wf[j], z);
        out[b] = 1.0f / (1.0f + __expf(-z));
    }
}

extern "C" void kernel_launch(void* const* d_in, const int* in_sizes, int n_in,
                              void* d_out, int out_size, void* d_ws, size_t ws_size,
                              hipStream_t stream) {
    const int*   x   = (const int*)d_in[0];
    const float* Emb = (const float*)d_in[1];
    const float* W   = (const float*)d_in[2];
    const float* bb  = (const float*)d_in[3];
    const float* h   = (const float*)d_in[4];
    const float* W1  = (const float*)d_in[5];
    const float* b1  = (const float*)d_in[6];
    const float* W2  = (const float*)d_in[7];
    const float* b2  = (const float*)d_in[8];
    const float* Wf  = (const float*)d_in[9];
    const float* bf  = (const float*)d_in[10];
    float* out = (float*)d_out;

    afm_kernel<<<1024, kNT, 0, stream>>>(x, Emb, W, bb, h, W1, b1, W2, b2, Wf, bf, out);
}